// Round 8
// baseline (46.863 us; speedup 1.0000x reference)
//
#include <hip/hip_runtime.h>
#include <hip/hip_bf16.h>
#include <stdint.h>

// RelativePositionalEmbedding: out[bh, q, k] = dot(q[bh,q,:], pos_emb[q-k+1023,:]) / 8
// B*H = 32, L = 1024, D = 64. Output (32,1024,1024) fp32 = 134 MB -> write-BW-bound.
//
// R7: SINGLE kernel. P is staged per-band via registers (8KB fp32 coalesced ->
// in-register f2b cvt -> ds_write_b128 with XOR swizzle on the write address;
// rule #21 satisfied: swizzled write + swizzled read, no global_load_lds).
// Per-wave-private buffers -> no barriers; compiler manages all waitcnts
// (no manual vmcnt FIFO to get wrong). Keeps: XCD-chunked q, interleaved
// pair-flush (256B runs), regular stores, Q fp32 direct with in-reg cvt.

#define LSEQ 1024
#define DDIM 64

typedef __attribute__((ext_vector_type(8))) short bf16x8;
typedef __attribute__((ext_vector_type(16))) float f32x16;

__device__ __forceinline__ unsigned short f2b(float f) {
  union { float f; unsigned u; } c; c.f = f;
  unsigned u = c.u;
  u += 0x7fffu + ((u >> 16) & 1u);   // round-to-nearest-even
  return (unsigned short)(u >> 16);
}

// One workgroup (4 waves) per q. Wave w owns columns [w*256, w*256+256), 8 tiles.
// mfma_f32_32x32x16_bf16: A row = lane&31, k = 16*s + 8*(lane>>5)+j
//                         B col = lane&31 (-> P row q+1023-n), same k
//                         D col = lane&31, row = (r&3)+8*(r>>2)+4*(lane>>5)
__global__ __launch_bounds__(256) void rpe_kernel(
    const float* __restrict__ Qf, const float* __restrict__ Pf,
    float* __restrict__ out) {
  __shared__ short lds[4][2][2048];           // [wave][buf][4KB bf16 band]
  // XCD-chunked q: XCD x gets q in [x*128, x*128+128) (1024 = 8*128, bijective)
  const int bid  = (int)blockIdx.x;
  const int q    = ((bid & 7) << 7) + (bid >> 3);
  const int tid  = (int)threadIdx.x;
  const int lane = tid & 63;
  const int wave = tid >> 6;
  const int l31  = lane & 31;
  const int hi   = lane >> 5;
  const int nbase = wave << 8;

  // --- P band reg-staging geometry ---
  // Band tt = P rows [lo, lo+32), lo = q + 992 - nbase - 32*tt (fp32, 256B/row).
  // Lane covers row rl = lane>>1, half hl = lane&1 (32 floats = 8 float4),
  // fully coalesced (consecutive lanes -> consecutive 128B).
  const int rl = lane >> 1;
  const int hl = lane & 1;
  const int sw = rl & 7;                      // XOR swizzle key (row&7)
  // float4 base for band 0 at this lane:
  const float4* P4 = (const float4*)Pf;
  const size_t base4 = ((size_t)(q + 992 - nbase + rl) << 4) + (hl << 3);

  float4 pr[8];                               // staged band (32 VGPR)
  auto LOADB = [&](int tt) {
    const float4* s = P4 + (base4 - ((size_t)tt << 9));   // -32 rows * 16 f4
#pragma unroll
    for (int j = 0; j < 8; ++j) pr[j] = s[j];
  };
  // LDS row = 64 shorts (128B) = 8 slots of 16B. Lane writes slots
  // s16 = hl*4 + j, swizzled ^ (rl&7). Slot s16 holds cols [8*s16, 8*s16+8).
  auto WRITEB = [&](int buf) {
    short* dst = &lds[wave][buf][rl << 6];
#pragma unroll
    for (int j = 0; j < 4; ++j) {
      const float4 u = pr[2 * j], v = pr[2 * j + 1];
      bf16x8 w;
      w[0] = (short)f2b(u.x); w[1] = (short)f2b(u.y);
      w[2] = (short)f2b(u.z); w[3] = (short)f2b(u.w);
      w[4] = (short)f2b(v.x); w[5] = (short)f2b(v.y);
      w[6] = (short)f2b(v.z); w[7] = (short)f2b(v.w);
      *(bf16x8*)(dst + (((((hl << 2) + j)) ^ sw) << 3)) = w;
    }
  };

  LOADB(0);
  WRITEB(0);                                  // startup stall only
  LOADB(1);

  // A fragments from fp32 Q, scaled by 1/8 (exact) and converted in-register.
  bf16x8 a[4];
  {
    const float* qp = Qf + ((size_t)((l31 << 10) + q)) * DDIM + (hi << 3);
#pragma unroll
    for (int s = 0; s < 4; ++s) {
      float4 u = *(const float4*)(qp + 16 * s);
      float4 v = *(const float4*)(qp + 16 * s + 4);
      bf16x8 t;
      t[0] = (short)f2b(u.x * 0.125f); t[1] = (short)f2b(u.y * 0.125f);
      t[2] = (short)f2b(u.z * 0.125f); t[3] = (short)f2b(u.w * 0.125f);
      t[4] = (short)f2b(v.x * 0.125f); t[5] = (short)f2b(v.y * 0.125f);
      t[6] = (short)f2b(v.z * 0.125f); t[7] = (short)f2b(v.w * 0.125f);
      a[s] = t;
    }
  }

  const int rr = 31 - l31;                    // LDS row this lane reads
  const int rx = rr & 7;                      // read-side XOR key

  f32x16 accA, accB;
#pragma unroll
  for (int t = 0; t < 8; ++t) {
    // buf[t&1] holds band t (written at t-1 / prologue).
    if (t < 7) WRITEB((t + 1) & 1);           // write band t+1 (consumes pr)
    if (t < 6) LOADB(t + 2);                  // issue loads for band t+2

    f32x16& acc = (t & 1) ? accB : accA;
#pragma unroll
    for (int r = 0; r < 16; ++r) acc[r] = 0.0f;

    const short* base = &lds[wave][t & 1][rr << 6];
#pragma unroll
    for (int s = 0; s < 4; ++s) {
      bf16x8 bfr = *(const bf16x8*)(base + (((hi + 2 * s) ^ rx) << 3));
      acc = __builtin_amdgcn_mfma_f32_32x32x16_bf16(a[s], bfr, acc, 0, 0, 0);
    }

    if (t & 1) {
      // flush tiles (t-1, t): per m-plane two adjacent 128B lines = 256B run
      float* ob = out + ((size_t)hi << 22) + (q << 10) + nbase + ((t - 1) << 5) + l31;
#pragma unroll
      for (int r = 0; r < 16; ++r) {
        const int m = (r & 3) + 8 * (r >> 2);
        ob[(size_t)m << 20]        = accA[r];
        ob[((size_t)m << 20) + 32] = accB[r];
      }
    }
  }
}

extern "C" void kernel_launch(void* const* d_in, const int* in_sizes, int n_in,
                              void* d_out, int out_size, void* d_ws, size_t ws_size,
                              hipStream_t stream) {
  const float* qin = (const float*)d_in[0];
  // d_in[1] (k) unused: only its length (1024) matters, which is fixed.
  const float* pin = (const float*)d_in[2];
  (void)d_ws; (void)ws_size;

  rpe_kernel<<<1024, 256, 0, stream>>>(qin, pin, (float*)d_out);
}